// Round 4
// baseline (132.962 us; speedup 1.0000x reference)
//
#include <hip/hip_runtime.h>
#include <hip/hip_bf16.h>

typedef float f32x4 __attribute__((ext_vector_type(4)));
typedef unsigned int u32x4 __attribute__((ext_vector_type(4)));
typedef short s16x8 __attribute__((ext_vector_type(8)));

#define L2E 1.44269504088896340736f

static __device__ __forceinline__ unsigned int bf16_rne(float f) {
    unsigned int u = __builtin_bit_cast(unsigned int, f);
    return (u + 0x7fffu + ((u >> 16) & 1u)) >> 16;
}
static __device__ __forceinline__ unsigned int pack_bf16x2(float lo, float hi) {
    return bf16_rne(lo) | (bf16_rne(hi) << 16);
}
static __device__ __forceinline__ unsigned int cvt_pk_bf16(float lo, float hi) {
    unsigned int r;
    asm("v_cvt_pk_bf16_f32 %0, %1, %2" : "=v"(r) : "v"(lo), "v"(hi));
    return r;
}

// ---------------------------------------------------------------------------
// Prep: q' = (q+pos)*0.125*log2e -> bf16 [b][t][c] (linear);
//       k' = (k+pos) -> bf16 FRAGMENT-MAJOR: ((b*128+s16)*2+kc)*512 + lane*8+j
//            element K[16*s16 + (lane&15)][32*kc + 8*(lane>>4) + j]
//       v' = (v+pos) -> bf16 FRAGMENT-MAJOR: (((b*32+sb)*4+n)*2+kc2)*512 + lane*8+j
//            element V[16*n + (lane&15)][64*sb + 32*kc2 + 8*(lane>>4) + j]
// So the attention kernel's MFMA operand loads are single coalesced 1KB reads.
// ---------------------------------------------------------------------------
__global__ __launch_bounds__(256) void qkv_prep(const float* __restrict__ qkv,
                                                const float* __restrict__ pos,
                                                unsigned short* __restrict__ qs,
                                                unsigned short* __restrict__ ktf,
                                                unsigned short* __restrict__ vtf)
{
    __shared__ unsigned short QtS[64][72];
    __shared__ unsigned short KtS[64][72];
    const int b    = blockIdx.y;
    const int t0   = blockIdx.x * 64;
    const int i    = threadIdx.x;
    const int crow = i >> 2;          // 0..63 : channel row
    const int t16  = (i & 3) * 16;    // 0,16,32,48 : t offset
    const float QSCALE = 0.125f * L2E;

    float pr[16];
    {
        const f32x4* pp = reinterpret_cast<const f32x4*>(
            pos + ((size_t)(b * 64 + crow)) * 2048 + t0 + t16);
        #pragma unroll
        for (int j = 0; j < 4; ++j) {
            f32x4 v = __builtin_nontemporal_load(pp + j);
            pr[4*j+0] = v[0]; pr[4*j+1] = v[1]; pr[4*j+2] = v[2]; pr[4*j+3] = v[3];
        }
    }
    const float* qp = qkv + ((size_t)(b * 192 + crow)) * 2048 + t0 + t16;
    {   // Q -> LDS transposed, scaled
        #pragma unroll
        for (int j = 0; j < 4; ++j) {
            f32x4 v = __builtin_nontemporal_load(reinterpret_cast<const f32x4*>(qp) + j);
            #pragma unroll
            for (int e = 0; e < 4; ++e)
                QtS[t16 + 4*j + e][crow] =
                    (unsigned short)bf16_rne((v[e] + pr[4*j+e]) * QSCALE);
        }
    }
    {   // K -> LDS transposed
        const float* kp = qp + (size_t)64 * 2048;
        #pragma unroll
        for (int j = 0; j < 4; ++j) {
            f32x4 v = __builtin_nontemporal_load(reinterpret_cast<const f32x4*>(kp) + j);
            #pragma unroll
            for (int e = 0; e < 4; ++e)
                KtS[t16 + 4*j + e][crow] =
                    (unsigned short)bf16_rne(v[e] + pr[4*j+e]);
        }
    }
    {   // V: pack and write fragment-major directly from registers
        const float* vp = qp + (size_t)128 * 2048;
        unsigned int vv[8];
        #pragma unroll
        for (int j = 0; j < 4; ++j) {
            f32x4 v = __builtin_nontemporal_load(reinterpret_cast<const f32x4*>(vp) + j);
            vv[2*j+0] = pack_bf16x2(v[0] + pr[4*j+0], v[1] + pr[4*j+1]);
            vv[2*j+1] = pack_bf16x2(v[2] + pr[4*j+2], v[3] + pr[4*j+3]);
        }
        const int n   = crow >> 4;
        const int lnv = crow & 15;
        const int sb  = t0 >> 6;   // == blockIdx.x
        #pragma unroll
        for (int h = 0; h < 2; ++h) {
            const int soff = t16 + 8 * h;
            const int kc2  = soff >> 5;
            const int lgv  = (soff >> 3) & 3;
            unsigned short* dst = vtf +
                ((((size_t)(b * 32 + sb)) * 4 + n) * 2 + kc2) * 512 +
                (lnv + 16 * lgv) * 8;
            *reinterpret_cast<u32x4*>(dst) =
                (u32x4){vv[4*h+0], vv[4*h+1], vv[4*h+2], vv[4*h+3]};
        }
    }
    __syncthreads();
    {   // Q out [t][c] linear
        const int trow = i >> 2;
        const int c16  = (i & 3) * 16;
        u32x4 a0 = *reinterpret_cast<const u32x4*>(&QtS[trow][c16]);
        u32x4 a1 = *reinterpret_cast<const u32x4*>(&QtS[trow][c16 + 8]);
        unsigned short* qd = qs + ((size_t)(b * 2048 + t0 + trow)) * 64 + c16;
        reinterpret_cast<u32x4*>(qd)[0] = a0;
        reinterpret_cast<u32x4*>(qd)[1] = a1;
    }
    {   // K out fragment-major
        const int g   = i >> 6;        // 0..3 : s16 sub-tile
        const int l   = i & 63;        // lane slot
        const int lnk = l & 15;
        const int lgk = l >> 4;
        #pragma unroll
        for (int kc = 0; kc < 2; ++kc) {
            u32x4 d = *reinterpret_cast<const u32x4*>(
                &KtS[16 * g + lnk][32 * kc + 8 * lgk]);
            unsigned short* dst = ktf +
                (((size_t)(b * 128 + (t0 >> 4) + g)) * 2 + kc) * 512 + l * 8;
            *reinterpret_cast<u32x4*>(dst) = d;
        }
    }
}

// ---------------------------------------------------------------------------
// LDS-free, barrier-free flash attention. All MFMA operands loaded directly
// from fragment-major workspace (coalesced 1KB/wave); mask per-lane registers.
// K+mask prefetched one s-tile ahead with static A/B register sets.
// ---------------------------------------------------------------------------
__device__ __forceinline__ void load_kfrag(s16x8 (&kf)[2][4],
        const unsigned short* __restrict__ ktf, size_t bk, int lane, int st)
{
    #pragma unroll
    for (int kc = 0; kc < 2; ++kc)
        #pragma unroll
        for (int ti = 0; ti < 4; ++ti)
            kf[kc][ti] = *reinterpret_cast<const s16x8*>(
                ktf + ((bk + 4 * st + ti) * 2 + kc) * 512 + lane * 8);
}

template<bool MB>
__device__ __forceinline__ void load_mask(unsigned int (&mf)[4],
        const void* __restrict__ maskp, size_t mrowoff, int lg, int st)
{
    if (MB) {
        const unsigned char* mp = (const unsigned char*)maskp + mrowoff + st * 64 + 4 * lg;
        #pragma unroll
        for (int ti = 0; ti < 4; ++ti)
            mf[ti] = __builtin_nontemporal_load(
                reinterpret_cast<const unsigned int*>(mp + 16 * ti));
    } else {
        const unsigned int* mp = (const unsigned int*)maskp + mrowoff + st * 64 + 4 * lg;
        #pragma unroll
        for (int ti = 0; ti < 4; ++ti) {
            u32x4 x = __builtin_nontemporal_load(
                reinterpret_cast<const u32x4*>(mp + 16 * ti));
            mf[ti] = (x[0] ? 1u : 0u) | ((x[1] ? 1u : 0u) << 8) |
                     ((x[2] ? 1u : 0u) << 16) | ((x[3] ? 1u : 0u) << 24);
        }
    }
}

__device__ __forceinline__ void attn_body(
        const s16x8 (&kf)[2][4], const unsigned int (&mf)[4],
        const s16x8 (&qf)[2], f32x4 (&acc)[4], float& M, float& L,
        const unsigned short* __restrict__ vtf, size_t bv,
        int lane, int ln, int lg, int st)
{
    // V fragments for this tile (issued first; latency hides under QK+softmax)
    s16x8 vf[2][4];
    #pragma unroll
    for (int kc2 = 0; kc2 < 2; ++kc2)
        #pragma unroll
        for (int n = 0; n < 4; ++n)
            vf[kc2][n] = *reinterpret_cast<const s16x8*>(
                vtf + (((bv + st) * 4 + n) * 2 + kc2) * 512 + lane * 8);

    // QK^T (swapped): S^T[s][t]; lane: s = 16ti+4lg+r, t = its q-row
    f32x4 S[4];
    #pragma unroll
    for (int ti = 0; ti < 4; ++ti) S[ti] = (f32x4){0.f, 0.f, 0.f, 0.f};
    __builtin_amdgcn_s_setprio(1);
    #pragma unroll
    for (int kc = 0; kc < 2; ++kc)
        #pragma unroll
        for (int ti = 0; ti < 4; ++ti)
            S[ti] = __builtin_amdgcn_mfma_f32_16x16x32_bf16(kf[kc][ti], qf[kc], S[ti], 0, 0, 0);
    __builtin_amdgcn_s_setprio(0);

    // mask + online softmax (S already in log2 units)
    float p[4][4];
    #pragma unroll
    for (int ti = 0; ti < 4; ++ti)
        #pragma unroll
        for (int r = 0; r < 4; ++r)
            p[ti][r] = ((mf[ti] >> (8 * r)) & 0xffu) ? -1e9f : S[ti][r];
    float tm = fmaxf(fmaxf(fmaxf(p[0][0], p[0][1]), fmaxf(p[0][2], p[0][3])),
                     fmaxf(fmaxf(p[1][0], p[1][1]), fmaxf(p[1][2], p[1][3])));
    tm = fmaxf(tm, fmaxf(fmaxf(fmaxf(p[2][0], p[2][1]), fmaxf(p[2][2], p[2][3])),
                         fmaxf(fmaxf(p[3][0], p[3][1]), fmaxf(p[3][2], p[3][3]))));
    tm = fmaxf(tm, __shfl_xor(tm, 16, 64));
    tm = fmaxf(tm, __shfl_xor(tm, 32, 64));
    if (!__all(tm <= M)) {           // T13: defer rescale
        const float Mn    = fmaxf(M, tm);
        const float alpha = exp2f(M - Mn);
        L *= alpha;
        #pragma unroll
        for (int n = 0; n < 4; ++n) acc[n] *= alpha;
        M = Mn;
    }
    float tsum = 0.f;
    #pragma unroll
    for (int ti = 0; ti < 4; ++ti)
        #pragma unroll
        for (int r = 0; r < 4; ++r) {
            p[ti][r] = exp2f(p[ti][r] - M);
            tsum += p[ti][r];
        }
    tsum += __shfl_xor(tsum, 16, 64);
    tsum += __shfl_xor(tsum, 32, 64);
    L += tsum;

    // pack P -> bf16, redistribute to PV B-fragment layout
    unsigned int pk[4][2];
    #pragma unroll
    for (int ti = 0; ti < 4; ++ti) {
        pk[ti][0] = cvt_pk_bf16(p[ti][0], p[ti][1]);
        pk[ti][1] = cvt_pk_bf16(p[ti][2], p[ti][3]);
    }
    unsigned int pfr[2][4];
    #pragma unroll
    for (int kc2 = 0; kc2 < 2; ++kc2)
        #pragma unroll
        for (int a2 = 0; a2 < 2; ++a2)
            #pragma unroll
            for (int b2 = 0; b2 < 2; ++b2)
                #pragma unroll
                for (int e = 0; e < 2; ++e) {
                    int src = ln + 16 * (2 * (lg & 1) + e);
                    unsigned int v = (unsigned int)__shfl(
                        (int)pk[2 * kc2 + a2][b2], src, 64);
                    if ((lg >> 1) == a2) pfr[kc2][2 * e + b2] = v;
                }

    // PV: O^T[c][t] += V^T · P^T
    __builtin_amdgcn_s_setprio(1);
    #pragma unroll
    for (int kc2 = 0; kc2 < 2; ++kc2) {
        union { unsigned int u[4]; s16x8 s; } pu;
        pu.u[0] = pfr[kc2][0]; pu.u[1] = pfr[kc2][1];
        pu.u[2] = pfr[kc2][2]; pu.u[3] = pfr[kc2][3];
        #pragma unroll
        for (int n = 0; n < 4; ++n)
            acc[n] = __builtin_amdgcn_mfma_f32_16x16x32_bf16(vf[kc2][n], pu.s, acc[n], 0, 0, 0);
    }
    __builtin_amdgcn_s_setprio(0);
}

template<bool MB>
__device__ __forceinline__ void attn_run(
        const unsigned short* __restrict__ qs,
        const unsigned short* __restrict__ ktf,
        const unsigned short* __restrict__ vtf,
        const void* __restrict__ maskp,
        float* __restrict__ out, int b, int t0, int tid)
{
    const int wave = tid >> 6;
    const int lane = tid & 63;
    const int ln   = lane & 15;
    const int lg   = lane >> 4;
    const int tg   = t0 + 16 * wave + ln;     // this lane's q row

    s16x8 qf[2];
    #pragma unroll
    for (int kc = 0; kc < 2; ++kc)
        qf[kc] = *reinterpret_cast<const s16x8*>(
            qs + ((size_t)(b * 2048 + tg)) * 64 + 32 * kc + 8 * lg);

    f32x4 acc[4];
    #pragma unroll
    for (int n = 0; n < 4; ++n) acc[n] = (f32x4){0.f, 0.f, 0.f, 0.f};
    float M = -3.0e38f, L = 0.0f;

    const size_t bk = (size_t)b * 128;
    const size_t bv = (size_t)b * 32;
    const size_t mrowoff = ((size_t)b * 2048 + (size_t)tg) * 2048;

    s16x8 fka[2][4], fkb[2][4];
    unsigned int fm0[4], fm1[4];
    load_kfrag(fka, ktf, bk, lane, 0);
    load_mask<MB>(fm0, maskp, mrowoff, lg, 0);

    #pragma unroll 1
    for (int sb = 0; sb < 32; sb += 2) {
        load_kfrag(fkb, ktf, bk, lane, sb + 1);
        load_mask<MB>(fm1, maskp, mrowoff, lg, sb + 1);
        attn_body(fka, fm0, qf, acc, M, L, vtf, bv, lane, ln, lg, sb);
        if (sb + 2 < 32) {
            load_kfrag(fka, ktf, bk, lane, sb + 2);
            load_mask<MB>(fm0, maskp, mrowoff, lg, sb + 2);
        }
        attn_body(fkb, fm1, qf, acc, M, L, vtf, bv, lane, ln, lg, sb + 1);
    }

    const float inv = 1.0f / L;
    #pragma unroll
    for (int n = 0; n < 4; ++n)
        #pragma unroll
        for (int r = 0; r < 4; ++r)
            __builtin_nontemporal_store(
                acc[n][r] * inv,
                &out[((size_t)(b * 64 + 16 * n + 4 * lg + r)) * 2048 + tg]);
}

__global__ __launch_bounds__(256, 2) void attn_kernel(
        const unsigned short* __restrict__ qs,
        const unsigned short* __restrict__ ktf,
        const unsigned short* __restrict__ vtf,
        const void* __restrict__ maskp,
        float* __restrict__ out)
{
    // XCD-aware swizzle: XCD (id&7) hosts batches {id&7, (id&7)+8} only,
    // so each XCD's L2 sees <=2 batches' K/V stream.
    const int id = blockIdx.x;
    const int b  = (id & 7) + 8 * ((id >> 3) & 1);
    const int t0 = (id >> 4) * 64;

    // mask dtype detection (uniform): int32 0/1 has zero high bytes
    unsigned int accm = 0;
    {
        const unsigned int* mu = (const unsigned int*)maskp;
        #pragma unroll
        for (int j = 0; j < 16; ++j) accm |= mu[j];
    }
    if ((accm & 0xffffff00u) != 0u)
        attn_run<true >(qs, ktf, vtf, maskp, out, b, t0, threadIdx.x);
    else
        attn_run<false>(qs, ktf, vtf, maskp, out, b, t0, threadIdx.x);
}

extern "C" void kernel_launch(void* const* d_in, const int* in_sizes, int n_in,
                              void* d_out, int out_size, void* d_ws, size_t ws_size,
                              hipStream_t stream) {
    const float* qkv = (const float*)d_in[0];
    const float* pos = (const float*)d_in[1];
    const void*  msk = d_in[2];
    float* outp = (float*)d_out;
    unsigned short* ws = (unsigned short*)d_ws;
    const size_t PLANE = (size_t)16 * 2048 * 64;   // 2M shorts per plane
    unsigned short* qs  = ws;
    unsigned short* ktf = ws + PLANE;
    unsigned short* vtf = ws + 2 * PLANE;

    dim3 pgrid(2048 / 64, 16);
    qkv_prep<<<pgrid, 256, 0, stream>>>(qkv, pos, qs, ktf, vtf);
    attn_kernel<<<512, 256, 0, stream>>>(qs, ktf, vtf, msk, outp);
}